// Round 8
// baseline (524.672 us; speedup 1.0000x reference)
//
#include <hip/hip_runtime.h>
#include <math.h>

// FlashSVDRoPEAttention — round 8 (round-7 resubmit; R7 was an acquisition timeout).
// prep (rope tab + VT bf16) -> qkv_proj_mfma (LDS tab + LDS out-bounce) -> flash.
// Flash: unpaired heavy-first grid 2048 (8 blocks/CU), XCD-aware bh grouping,
// reg-prefetch staging, shfl-based mask, ones-MFMA l-sum, defer-max, exp2.

#define B_ 4
#define H_ 16
#define M_ 2048
#define R_ 32
#define DH_ 64
#define BH_ 64
#define NEGV -1.0e30f
#define LOG2E 1.4426950408889634f

typedef float  f32x4  __attribute__((ext_vector_type(4)));
typedef __bf16 bf16x8 __attribute__((ext_vector_type(8)));
typedef unsigned short u16x4 __attribute__((ext_vector_type(4)));
typedef unsigned short u16x8 __attribute__((ext_vector_type(8)));

__device__ __forceinline__ unsigned short bfbits(float f) {
    __bf16 h = (__bf16)f;
    return __builtin_bit_cast(unsigned short, h);
}

// ---------------------------------------------------------------------------
// prep: [0, 131072) rope cos/sin table; [131072, 229376) VT bf16 transpose.
// tab[bm][0..15]=cos, [16..31]=sin (fi=(d&31)>>1). VTb[mat][h][d][r].
// ---------------------------------------------------------------------------
__global__ void prep_kernel(const int* __restrict__ pid,
                            const float* __restrict__ Vq,
                            const float* __restrict__ Vk,
                            const float* __restrict__ Vv,
                            float* __restrict__ tab,
                            unsigned short* __restrict__ VTb)
{
    const int idx = blockIdx.x * 256 + threadIdx.x;
    if (idx < B_ * M_ * 16) {
        const int bm = idx >> 4, fi = idx & 15;
        // 10000^(-fi/32) = 2^(-fi * log2(10000)/32)
        const float invf = exp2f((float)fi * -0.4152410118609203f);
        const float ang  = (float)pid[bm] * invf;
        float s, c;
        sincosf(ang, &s, &c);
        tab[(size_t)bm * 32 + fi]      = c;
        tab[(size_t)bm * 32 + 16 + fi] = s;
    } else {
        const int k = idx - B_ * M_ * 16;          // 0..98303
        const float* src = (k < 32768) ? Vq : ((k < 65536) ? Vk : Vv);
        const int rem = k & 32767;
        const int h = rem >> 11, d = (rem >> 5) & 63, r = rem & 31;
        VTb[k] = bfbits(src[(h * 32 + r) * 64 + d]);
    }
}

// ---------------------------------------------------------------------------
// Projection via MFMA (K=32=R). P tile + tab slice staged in LDS (coalesced);
// RoPE'd outputs bounced through LDS so global stores are coalesced u16x8.
//   A-frag: lane c+16g holds A[row=c][k=g*8+e]
//   D:      lane c+16g holds D[Arow=4g+reg][Brow=c]
// mat 0/1: RoPE epilogue (partner d^32 = di^2, same lane) -> Qb/Kb rows.
// mat 2:   writes Vt[bh][d][phi-pos] directly (pos = 8g + 4mi + reg).
// ---------------------------------------------------------------------------
__global__ __launch_bounds__(256) void qkv_proj_mfma_kernel(
    const float* __restrict__ Pq, const float* __restrict__ Pk,
    const float* __restrict__ Pv,
    const unsigned short* __restrict__ VTb,
    const float* __restrict__ bq, const float* __restrict__ bk,
    const float* __restrict__ bv,
    const float* __restrict__ tab,
    unsigned short* __restrict__ Qb, unsigned short* __restrict__ Kb,
    unsigned short* __restrict__ Vt)
{
    __shared__ unsigned short Ps[128 * 40];   // P tile bf16 (pad 40)
    __shared__ float Tabs[128 * 32];          // cos/sin slice for this m-chunk
    __shared__ unsigned short Os[128 * 72];   // out bounce (pad 72: 16B-aligned rows)

    const int mat = blockIdx.z, bh = blockIdx.y, m0 = blockIdx.x * 128;
    const int h = bh & (H_ - 1), b = bh >> 4;
    const int t = threadIdx.x, w = t >> 6, lane = t & 63;
    const int c16 = lane & 15, g = lane >> 4, g8 = g << 3;

    const float* P    = (mat == 0) ? Pq : ((mat == 1) ? Pk : Pv);
    const float* bias = (mat == 0) ? bq : ((mat == 1) ? bk : bv);
    const float scl = (mat == 0) ? 0.125f * LOG2E : 1.0f;

    // stage P[128][32] fp32 -> bf16 LDS, fully coalesced
    const float* Pg = P + ((size_t)bh * M_ + m0) * 32;
    #pragma unroll
    for (int pass = 0; pass < 4; ++pass) {
        const int lin = pass * 256 + t;           // float4 unit
        const int row = lin >> 3, c4 = (lin & 7) << 2;
        const f32x4 v = *(const f32x4*)&Pg[row * 32 + c4];
        u16x4 b4;
        #pragma unroll
        for (int e = 0; e < 4; ++e) b4[e] = bfbits(v[e]);
        *(u16x4*)&Ps[row * 40 + c4] = b4;
    }
    // stage tab slice (mats 0/1 only), coalesced f32x4
    if (mat != 2) {
        const float* tg = tab + ((size_t)b * M_ + m0) * 32;
        #pragma unroll
        for (int pass = 0; pass < 4; ++pass) {
            const int lin = pass * 256 + t;
            *(f32x4*)&Tabs[lin << 2] = *(const f32x4*)&tg[lin << 2];
        }
    }

    bf16x8 vf[4];
    #pragma unroll
    for (int di = 0; di < 4; ++di)
        vf[di] = *(const bf16x8*)&VTb[((size_t)((mat * 16 + h) * 64 + di * 16 + c16)) * 32 + g8];

    __syncthreads();

    bf16x8 af[2];
    #pragma unroll
    for (int mi = 0; mi < 2; ++mi)
        af[mi] = *(const bf16x8*)&Ps[(w * 32 + mi * 16 + c16) * 40 + g8];

    f32x4 acc[2][4];
    const f32x4 z4 = {0.f, 0.f, 0.f, 0.f};
    #pragma unroll
    for (int mi = 0; mi < 2; ++mi)
        #pragma unroll
        for (int di = 0; di < 4; ++di)
            acc[mi][di] = __builtin_amdgcn_mfma_f32_16x16x32_bf16(af[mi], vf[di], z4, 0, 0, 0);

    float bsv[4];
    #pragma unroll
    for (int di = 0; di < 4; ++di) bsv[di] = bias[h * 64 + di * 16 + c16];

    if (mat == 2) {
        #pragma unroll
        for (int di = 0; di < 4; ++di) {
            u16x8 v8;
            #pragma unroll
            for (int mi = 0; mi < 2; ++mi)
                #pragma unroll
                for (int reg = 0; reg < 4; ++reg)
                    v8[(mi << 2) | reg] = bfbits(acc[mi][di][reg] + bsv[di]);
            const int d = di * 16 + c16;
            *(u16x8*)&Vt[((size_t)(bh * 64 + d)) * M_ + m0 + w * 32 + g8] = v8;
        }
        __syncthreads();   // match mats 0/1 barrier count (per-block anyway)
    } else {
        // RoPE into LDS bounce tile
        #pragma unroll
        for (int mi = 0; mi < 2; ++mi)
            #pragma unroll
            for (int reg = 0; reg < 4; ++reg) {
                const int mloc = w * 32 + mi * 16 + (g << 2) + reg;
                const float x0 = acc[mi][0][reg] + bsv[0];
                const float x1 = acc[mi][1][reg] + bsv[1];
                const float x2 = acc[mi][2][reg] + bsv[2];
                const float x3 = acc[mi][3][reg] + bsv[3];
                const int fi = c16 >> 1;
                const float c0 = Tabs[mloc * 32 + fi],     s0 = Tabs[mloc * 32 + 16 + fi];
                const float c1 = Tabs[mloc * 32 + 8 + fi], s1 = Tabs[mloc * 32 + 24 + fi];
                Os[mloc * 72 + c16]      = bfbits((x0 * c0 - x2 * s0) * scl);
                Os[mloc * 72 + 16 + c16] = bfbits((x1 * c1 - x3 * s1) * scl);
                Os[mloc * 72 + 32 + c16] = bfbits((x0 * s0 + x2 * c0) * scl);
                Os[mloc * 72 + 48 + c16] = bfbits((x1 * s1 + x3 * c1) * scl);
            }
        __syncthreads();
        // coalesced u16x8 write-out
        unsigned short* Outg = ((mat == 0) ? Qb : Kb) + ((size_t)bh * M_ + m0) * 64;
        #pragma unroll
        for (int pass = 0; pass < 4; ++pass) {
            const int lin = pass * 256 + t;
            const int row = lin >> 3, seg = lin & 7;
            *(u16x8*)&Outg[row * 64 + seg * 8] = *(const u16x8*)&Os[row * 72 + seg * 8];
        }
    }
}

// ---------------------------------------------------------------------------
// Flash attention. Grid 2048, 1 q-tile/block, heavy-first within each XCD's
// bh group (xcd=bid&7 owns bh in [xcd*8, xcd*8+8): K/V set = 4MB = one L2).
// Block = 64 q-rows, 4 waves x 16 rows, 8 blocks/CU.
// ---------------------------------------------------------------------------
__global__ __launch_bounds__(256, 8) void flash_mfma_kernel(
    const unsigned short* __restrict__ Qus, const unsigned short* __restrict__ Kus,
    const unsigned short* __restrict__ Vtus, const int* __restrict__ amask,
    float* __restrict__ out)
{
    __shared__ unsigned short Ks[64 * 72];
    __shared__ unsigned short Vts[64 * 72];

    const int bid = blockIdx.x;
    const int xcd = bid & 7, loc = bid >> 3;
    const int bh  = xcd * 8 + (loc & 7);
    const int qt  = 31 - (loc >> 3);          // heavy tiles dispatch first
    const int q0  = qt << 6;
    const int nkt = qt + 1;
    const int h = bh & (H_ - 1), b = bh >> 4;
    const int t = threadIdx.x;
    const int w = t >> 6, lane = t & 63;
    const int c16 = lane & 15, g = lane >> 4;
    const int g4 = g << 2, g8 = g << 3;
    const int w16 = w << 4;
    const int srow = t >> 2, sc0 = (t & 3) << 4;

    const unsigned short* Kg  = Kus  + (size_t)bh * M_ * 64;
    const unsigned short* Vtg = Vtus + (size_t)bh * 64 * M_;
    const f32x4 zero4 = {0.f, 0.f, 0.f, 0.f};

    bf16x8 onesf;
    #pragma unroll
    for (int e = 0; e < 8; ++e) onesf[e] = (__bf16)1.0f;

    bf16x8 qf[2];
    #pragma unroll
    for (int kkd = 0; kkd < 2; ++kkd)
        qf[kkd] = *(const bf16x8*)(Qus +
            ((size_t)bh * M_ + q0 + w16 + c16) * 64 + kkd * 32 + g8);
    const int qrow = q0 + w16 + c16;

    f32x4 oT[4];
    #pragma unroll
    for (int di = 0; di < 4; ++di) oT[di] = zero4;
    f32x4 lacc = zero4;
    float mr = -3.0e38f;

    // prefetch kt=0
    u16x8 kreg0, kreg1, vreg0, vreg1;
    int am_next;
    {
        const unsigned short* gk = Kg + (size_t)srow * 64 + sc0;
        kreg0 = *(const u16x8*)gk; kreg1 = *(const u16x8*)(gk + 8);
        const unsigned short* gv = Vtg + (size_t)srow * M_ + sc0;
        vreg0 = *(const u16x8*)gv; vreg1 = *(const u16x8*)(gv + 8);
        am_next = amask[b * M_ + lane];
    }

    for (int kt = 0; kt < nkt; ++kt) {
        const int n0 = kt << 6;
        const int am_cur = am_next;
        __syncthreads();
        *(u16x8*)&Ks[srow * 72 + sc0]      = kreg0;
        *(u16x8*)&Ks[srow * 72 + sc0 + 8]  = kreg1;
        *(u16x8*)&Vts[srow * 72 + sc0]     = vreg0;
        *(u16x8*)&Vts[srow * 72 + sc0 + 8] = vreg1;
        __syncthreads();

        if (kt + 1 < nkt) {
            const int n1 = n0 + 64;
            const unsigned short* gk = Kg + (size_t)(n1 + srow) * 64 + sc0;
            kreg0 = *(const u16x8*)gk; kreg1 = *(const u16x8*)(gk + 8);
            const unsigned short* gv = Vtg + (size_t)srow * M_ + n1 + sc0;
            vreg0 = *(const u16x8*)gv; vreg1 = *(const u16x8*)(gv + 8);
            am_next = amask[b * M_ + n1 + lane];
        }

        // ---- S^T = K . Q^T ----
        f32x4 st[4];
        #pragma unroll
        for (int ni = 0; ni < 4; ++ni) st[ni] = zero4;
        __builtin_amdgcn_s_setprio(1);
        #pragma unroll
        for (int kkd = 0; kkd < 2; ++kkd)
            #pragma unroll
            for (int ni = 0; ni < 4; ++ni) {
                const bf16x8 kf = *(const bf16x8*)&Ks[(ni * 16 + c16) * 72 + kkd * 32 + g8];
                st[ni] = __builtin_amdgcn_mfma_f32_16x16x32_bf16(kf, qf[kkd], st[ni], 0, 0, 0);
            }
        __builtin_amdgcn_s_setprio(0);

        // ---- softmax ----
        const bool allv  = __all(am_cur > 0);             // wave-uniform
        const bool needc = (n0 + 63) > (q0 + w16);        // wave-uniform
        bf16x8 pf[2];
        {
            float tm = -3.0e38f;
            if (allv) {
                if (needc) {
                    #pragma unroll
                    for (int ni = 0; ni < 4; ++ni)
                        #pragma unroll
                        for (int rg = 0; rg < 4; ++rg) {
                            const int n_loc = ni * 16 + g4 + rg;
                            const float sv = ((n0 + n_loc) <= qrow) ? st[ni][rg] : NEGV;
                            st[ni][rg] = sv;
                            tm = fmaxf(tm, sv);
                        }
                } else {
                    #pragma unroll
                    for (int ni = 0; ni < 4; ++ni)
                        #pragma unroll
                        for (int rg = 0; rg < 4; ++rg)
                            tm = fmaxf(tm, st[ni][rg]);
                }
            } else {
                #pragma unroll
                for (int ni = 0; ni < 4; ++ni)
                    #pragma unroll
                    for (int rg = 0; rg < 4; ++rg) {
                        const int n_loc = ni * 16 + g4 + rg;
                        const bool ok = ((n0 + n_loc) <= qrow) && (__shfl(am_cur, n_loc) > 0);
                        const float sv = ok ? st[ni][rg] : NEGV;
                        st[ni][rg] = sv;
                        tm = fmaxf(tm, sv);
                    }
            }
            tm = fmaxf(tm, __shfl_xor(tm, 16));
            tm = fmaxf(tm, __shfl_xor(tm, 32));
            const bool skip = __all(tm <= mr + 7.0f);
            if (!skip) {
                const float mnew  = fmaxf(mr, tm);
                const float alpha = exp2f(mr - mnew);
                mr = mnew;
                #pragma unroll
                for (int di = 0; di < 4; ++di)
                    #pragma unroll
                    for (int rg = 0; rg < 4; ++rg)
                        oT[di][rg] *= alpha;
                lacc[0] *= alpha;
            }
            if (allv) {
                #pragma unroll
                for (int ni = 0; ni < 4; ++ni)
                    #pragma unroll
                    for (int rg = 0; rg < 4; ++rg)
                        pf[ni >> 1][((ni & 1) << 2) | rg] =
                            (__bf16)exp2f(st[ni][rg] - mr);
            } else {
                #pragma unroll
                for (int ni = 0; ni < 4; ++ni)
                    #pragma unroll
                    for (int rg = 0; rg < 4; ++rg) {
                        const float sv = st[ni][rg];
                        const float pv = (sv > -1.0e29f) ? exp2f(sv - mr) : 0.f;
                        pf[ni >> 1][((ni & 1) << 2) | rg] = (__bf16)pv;
                    }
            }
        }

        // ---- l-sum + O^T += V^T . P^T (phi-permuted k, contiguous b128) ----
        __builtin_amdgcn_s_setprio(1);
        lacc = __builtin_amdgcn_mfma_f32_16x16x32_bf16(onesf, pf[0], lacc, 0, 0, 0);
        lacc = __builtin_amdgcn_mfma_f32_16x16x32_bf16(onesf, pf[1], lacc, 0, 0, 0);
        #pragma unroll
        for (int di = 0; di < 4; ++di)
            #pragma unroll
            for (int kk = 0; kk < 2; ++kk) {
                const bf16x8 vfr = *(const bf16x8*)&Vts[(di * 16 + c16) * 72 + kk * 32 + g8];
                oT[di] = __builtin_amdgcn_mfma_f32_16x16x32_bf16(vfr, pf[kk], oT[di], 0, 0, 0);
            }
        __builtin_amdgcn_s_setprio(0);
    }

    // ---- epilogue: f32x4 stores ----
    const float inv = (lacc[0] > 0.f) ? 1.f / lacc[0] : 0.f;
    const int q = q0 + w16 + c16;
    #pragma unroll
    for (int di = 0; di < 4; ++di) {
        f32x4 ov;
        #pragma unroll
        for (int rg = 0; rg < 4; ++rg) ov[rg] = oT[di][rg] * inv;
        *(f32x4*)&out[((size_t)(b * M_ + q) * H_ + h) * 64 + di * 16 + g4] = ov;
    }
}

// ---------------------------------------------------------------------------
extern "C" void kernel_launch(void* const* d_in, const int* in_sizes, int n_in,
                              void* d_out, int out_size, void* d_ws, size_t ws_size,
                              hipStream_t stream)
{
    const float* Pq = (const float*)d_in[0];
    const float* Pk = (const float*)d_in[1];
    const float* Pv = (const float*)d_in[2];
    const float* Vq = (const float*)d_in[3];
    const float* Vk = (const float*)d_in[4];
    const float* Vv = (const float*)d_in[5];
    const float* bq = (const float*)d_in[6];
    const float* bk = (const float*)d_in[7];
    const float* bv = (const float*)d_in[8];
    const int*   am = (const int*)d_in[9];
    const int*   pid = (const int*)d_in[10];
    float* out = (float*)d_out;

    // workspace: tab 1MB | VTb 192KB (@1MB) | Qb,Kb,Vt bf16 16MB each (@2MB)
    float* tab = (float*)d_ws;
    unsigned short* VTb = (unsigned short*)((char*)d_ws + (1 << 20));
    unsigned short* Qb  = (unsigned short*)((char*)d_ws + (2 << 20));
    unsigned short* Kb = Qb + (size_t)B_ * H_ * M_ * 64;
    unsigned short* Vt = Kb + (size_t)B_ * H_ * M_ * 64;

    prep_kernel<<<dim3((B_ * M_ * 16 + 98304) / 256), dim3(256), 0, stream>>>(
        pid, Vq, Vk, Vv, tab, VTb);

    qkv_proj_mfma_kernel<<<dim3(16, 64, 3), dim3(256), 0, stream>>>(
        Pq, Pk, Pv, VTb, bq, bk, bv, tab, Qb, Kb, Vt);

    flash_mfma_kernel<<<dim3(2048), dim3(256), 0, stream>>>(
        Qb, Kb, Vt, am, out);
}

// Round 9
// 189.373 us; speedup vs baseline: 2.7706x; 2.7706x over previous
//
#include <hip/hip_runtime.h>
#include <math.h>

// FlashSVDRoPEAttention — round 9.
// R8 regression root-caused: __launch_bounds__(256,8) forced VGPR 64->32 ->
// full spill (1.78GB scratch traffic). Reverted to (256,4); VGPR=64 + LDS
// 18.4KB naturally allow 8 blocks/CU residency without the allocator cap.
// Everything else kept from R8: unpaired heavy-first grid 2048, XCD-aware bh
// grouping, shfl mask, proj LDS-bounce, tab-in-LDS, exp2 prep.

#define B_ 4
#define H_ 16
#define M_ 2048
#define R_ 32
#define DH_ 64
#define BH_ 64
#define NEGV -1.0e30f
#define LOG2E 1.4426950408889634f

typedef float  f32x4  __attribute__((ext_vector_type(4)));
typedef __bf16 bf16x8 __attribute__((ext_vector_type(8)));
typedef unsigned short u16x4 __attribute__((ext_vector_type(4)));
typedef unsigned short u16x8 __attribute__((ext_vector_type(8)));

__device__ __forceinline__ unsigned short bfbits(float f) {
    __bf16 h = (__bf16)f;
    return __builtin_bit_cast(unsigned short, h);
}

// ---------------------------------------------------------------------------
// prep: [0, 131072) rope cos/sin table; [131072, 229376) VT bf16 transpose.
// tab[bm][0..15]=cos, [16..31]=sin (fi=(d&31)>>1). VTb[mat][h][d][r].
// ---------------------------------------------------------------------------
__global__ void prep_kernel(const int* __restrict__ pid,
                            const float* __restrict__ Vq,
                            const float* __restrict__ Vk,
                            const float* __restrict__ Vv,
                            float* __restrict__ tab,
                            unsigned short* __restrict__ VTb)
{
    const int idx = blockIdx.x * 256 + threadIdx.x;
    if (idx < B_ * M_ * 16) {
        const int bm = idx >> 4, fi = idx & 15;
        // 10000^(-fi/32) = 2^(-fi * log2(10000)/32)
        const float invf = exp2f((float)fi * -0.4152410118609203f);
        const float ang  = (float)pid[bm] * invf;
        float s, c;
        sincosf(ang, &s, &c);
        tab[(size_t)bm * 32 + fi]      = c;
        tab[(size_t)bm * 32 + 16 + fi] = s;
    } else {
        const int k = idx - B_ * M_ * 16;          // 0..98303
        const float* src = (k < 32768) ? Vq : ((k < 65536) ? Vk : Vv);
        const int rem = k & 32767;
        const int h = rem >> 11, d = (rem >> 5) & 63, r = rem & 31;
        VTb[k] = bfbits(src[(h * 32 + r) * 64 + d]);
    }
}

// ---------------------------------------------------------------------------
// Projection via MFMA (K=32=R). P tile + tab slice staged in LDS (coalesced);
// RoPE'd outputs bounced through LDS so global stores are coalesced u16x8.
//   A-frag: lane c+16g holds A[row=c][k=g*8+e]
//   D:      lane c+16g holds D[Arow=4g+reg][Brow=c]
// mat 0/1: RoPE epilogue (partner d^32 = di^2, same lane) -> Qb/Kb rows.
// mat 2:   writes Vt[bh][d][phi-pos] directly (pos = 8g + 4mi + reg).
// ---------------------------------------------------------------------------
__global__ __launch_bounds__(256) void qkv_proj_mfma_kernel(
    const float* __restrict__ Pq, const float* __restrict__ Pk,
    const float* __restrict__ Pv,
    const unsigned short* __restrict__ VTb,
    const float* __restrict__ bq, const float* __restrict__ bk,
    const float* __restrict__ bv,
    const float* __restrict__ tab,
    unsigned short* __restrict__ Qb, unsigned short* __restrict__ Kb,
    unsigned short* __restrict__ Vt)
{
    __shared__ unsigned short Ps[128 * 40];   // P tile bf16 (pad 40)
    __shared__ float Tabs[128 * 32];          // cos/sin slice for this m-chunk
    __shared__ unsigned short Os[128 * 72];   // out bounce (pad 72: 16B-aligned rows)

    const int mat = blockIdx.z, bh = blockIdx.y, m0 = blockIdx.x * 128;
    const int h = bh & (H_ - 1), b = bh >> 4;
    const int t = threadIdx.x, w = t >> 6, lane = t & 63;
    const int c16 = lane & 15, g = lane >> 4, g8 = g << 3;

    const float* P    = (mat == 0) ? Pq : ((mat == 1) ? Pk : Pv);
    const float* bias = (mat == 0) ? bq : ((mat == 1) ? bk : bv);
    const float scl = (mat == 0) ? 0.125f * LOG2E : 1.0f;

    // stage P[128][32] fp32 -> bf16 LDS, fully coalesced
    const float* Pg = P + ((size_t)bh * M_ + m0) * 32;
    #pragma unroll
    for (int pass = 0; pass < 4; ++pass) {
        const int lin = pass * 256 + t;           // float4 unit
        const int row = lin >> 3, c4 = (lin & 7) << 2;
        const f32x4 v = *(const f32x4*)&Pg[row * 32 + c4];
        u16x4 b4;
        #pragma unroll
        for (int e = 0; e < 4; ++e) b4[e] = bfbits(v[e]);
        *(u16x4*)&Ps[row * 40 + c4] = b4;
    }
    // stage tab slice (mats 0/1 only), coalesced f32x4
    if (mat != 2) {
        const float* tg = tab + ((size_t)b * M_ + m0) * 32;
        #pragma unroll
        for (int pass = 0; pass < 4; ++pass) {
            const int lin = pass * 256 + t;
            *(f32x4*)&Tabs[lin << 2] = *(const f32x4*)&tg[lin << 2];
        }
    }

    bf16x8 vf[4];
    #pragma unroll
    for (int di = 0; di < 4; ++di)
        vf[di] = *(const bf16x8*)&VTb[((size_t)((mat * 16 + h) * 64 + di * 16 + c16)) * 32 + g8];

    __syncthreads();

    bf16x8 af[2];
    #pragma unroll
    for (int mi = 0; mi < 2; ++mi)
        af[mi] = *(const bf16x8*)&Ps[(w * 32 + mi * 16 + c16) * 40 + g8];

    f32x4 acc[2][4];
    const f32x4 z4 = {0.f, 0.f, 0.f, 0.f};
    #pragma unroll
    for (int mi = 0; mi < 2; ++mi)
        #pragma unroll
        for (int di = 0; di < 4; ++di)
            acc[mi][di] = __builtin_amdgcn_mfma_f32_16x16x32_bf16(af[mi], vf[di], z4, 0, 0, 0);

    float bsv[4];
    #pragma unroll
    for (int di = 0; di < 4; ++di) bsv[di] = bias[h * 64 + di * 16 + c16];

    if (mat == 2) {
        #pragma unroll
        for (int di = 0; di < 4; ++di) {
            u16x8 v8;
            #pragma unroll
            for (int mi = 0; mi < 2; ++mi)
                #pragma unroll
                for (int reg = 0; reg < 4; ++reg)
                    v8[(mi << 2) | reg] = bfbits(acc[mi][di][reg] + bsv[di]);
            const int d = di * 16 + c16;
            *(u16x8*)&Vt[((size_t)(bh * 64 + d)) * M_ + m0 + w * 32 + g8] = v8;
        }
        __syncthreads();   // match mats 0/1 barrier count (per-block anyway)
    } else {
        // RoPE into LDS bounce tile
        #pragma unroll
        for (int mi = 0; mi < 2; ++mi)
            #pragma unroll
            for (int reg = 0; reg < 4; ++reg) {
                const int mloc = w * 32 + mi * 16 + (g << 2) + reg;
                const float x0 = acc[mi][0][reg] + bsv[0];
                const float x1 = acc[mi][1][reg] + bsv[1];
                const float x2 = acc[mi][2][reg] + bsv[2];
                const float x3 = acc[mi][3][reg] + bsv[3];
                const int fi = c16 >> 1;
                const float c0 = Tabs[mloc * 32 + fi],     s0 = Tabs[mloc * 32 + 16 + fi];
                const float c1 = Tabs[mloc * 32 + 8 + fi], s1 = Tabs[mloc * 32 + 24 + fi];
                Os[mloc * 72 + c16]      = bfbits((x0 * c0 - x2 * s0) * scl);
                Os[mloc * 72 + 16 + c16] = bfbits((x1 * c1 - x3 * s1) * scl);
                Os[mloc * 72 + 32 + c16] = bfbits((x0 * s0 + x2 * c0) * scl);
                Os[mloc * 72 + 48 + c16] = bfbits((x1 * s1 + x3 * c1) * scl);
            }
        __syncthreads();
        // coalesced u16x8 write-out
        unsigned short* Outg = ((mat == 0) ? Qb : Kb) + ((size_t)bh * M_ + m0) * 64;
        #pragma unroll
        for (int pass = 0; pass < 4; ++pass) {
            const int lin = pass * 256 + t;
            const int row = lin >> 3, seg = lin & 7;
            *(u16x8*)&Outg[row * 64 + seg * 8] = *(const u16x8*)&Os[row * 72 + seg * 8];
        }
    }
}

// ---------------------------------------------------------------------------
// Flash attention. Grid 2048, 1 q-tile/block, heavy-first within each XCD's
// bh group (xcd=bid&7 owns bh in [xcd*8, xcd*8+8): K/V set = 4MB = one L2).
// Block = 64 q-rows, 4 waves x 16 rows. launch_bounds(256,4): VGPR=64 (no
// spill — R8 lesson); HW residency still reaches 8 blocks/CU via VGPR+LDS.
// ---------------------------------------------------------------------------
__global__ __launch_bounds__(256, 4) void flash_mfma_kernel(
    const unsigned short* __restrict__ Qus, const unsigned short* __restrict__ Kus,
    const unsigned short* __restrict__ Vtus, const int* __restrict__ amask,
    float* __restrict__ out)
{
    __shared__ unsigned short Ks[64 * 72];
    __shared__ unsigned short Vts[64 * 72];

    const int bid = blockIdx.x;
    const int xcd = bid & 7, loc = bid >> 3;
    const int bh  = xcd * 8 + (loc & 7);
    const int qt  = 31 - (loc >> 3);          // heavy tiles dispatch first
    const int q0  = qt << 6;
    const int nkt = qt + 1;
    const int h = bh & (H_ - 1), b = bh >> 4;
    const int t = threadIdx.x;
    const int w = t >> 6, lane = t & 63;
    const int c16 = lane & 15, g = lane >> 4;
    const int g4 = g << 2, g8 = g << 3;
    const int w16 = w << 4;
    const int srow = t >> 2, sc0 = (t & 3) << 4;

    const unsigned short* Kg  = Kus  + (size_t)bh * M_ * 64;
    const unsigned short* Vtg = Vtus + (size_t)bh * 64 * M_;
    const f32x4 zero4 = {0.f, 0.f, 0.f, 0.f};

    bf16x8 onesf;
    #pragma unroll
    for (int e = 0; e < 8; ++e) onesf[e] = (__bf16)1.0f;

    bf16x8 qf[2];
    #pragma unroll
    for (int kkd = 0; kkd < 2; ++kkd)
        qf[kkd] = *(const bf16x8*)(Qus +
            ((size_t)bh * M_ + q0 + w16 + c16) * 64 + kkd * 32 + g8);
    const int qrow = q0 + w16 + c16;

    f32x4 oT[4];
    #pragma unroll
    for (int di = 0; di < 4; ++di) oT[di] = zero4;
    f32x4 lacc = zero4;
    float mr = -3.0e38f;

    // prefetch kt=0
    u16x8 kreg0, kreg1, vreg0, vreg1;
    int am_next;
    {
        const unsigned short* gk = Kg + (size_t)srow * 64 + sc0;
        kreg0 = *(const u16x8*)gk; kreg1 = *(const u16x8*)(gk + 8);
        const unsigned short* gv = Vtg + (size_t)srow * M_ + sc0;
        vreg0 = *(const u16x8*)gv; vreg1 = *(const u16x8*)(gv + 8);
        am_next = amask[b * M_ + lane];
    }

    for (int kt = 0; kt < nkt; ++kt) {
        const int n0 = kt << 6;
        const int am_cur = am_next;
        __syncthreads();
        *(u16x8*)&Ks[srow * 72 + sc0]      = kreg0;
        *(u16x8*)&Ks[srow * 72 + sc0 + 8]  = kreg1;
        *(u16x8*)&Vts[srow * 72 + sc0]     = vreg0;
        *(u16x8*)&Vts[srow * 72 + sc0 + 8] = vreg1;
        __syncthreads();

        if (kt + 1 < nkt) {
            const int n1 = n0 + 64;
            const unsigned short* gk = Kg + (size_t)(n1 + srow) * 64 + sc0;
            kreg0 = *(const u16x8*)gk; kreg1 = *(const u16x8*)(gk + 8);
            const unsigned short* gv = Vtg + (size_t)srow * M_ + n1 + sc0;
            vreg0 = *(const u16x8*)gv; vreg1 = *(const u16x8*)(gv + 8);
            am_next = amask[b * M_ + n1 + lane];
        }

        // ---- S^T = K . Q^T ----
        f32x4 st[4];
        #pragma unroll
        for (int ni = 0; ni < 4; ++ni) st[ni] = zero4;
        __builtin_amdgcn_s_setprio(1);
        #pragma unroll
        for (int kkd = 0; kkd < 2; ++kkd)
            #pragma unroll
            for (int ni = 0; ni < 4; ++ni) {
                const bf16x8 kf = *(const bf16x8*)&Ks[(ni * 16 + c16) * 72 + kkd * 32 + g8];
                st[ni] = __builtin_amdgcn_mfma_f32_16x16x32_bf16(kf, qf[kkd], st[ni], 0, 0, 0);
            }
        __builtin_amdgcn_s_setprio(0);

        // ---- softmax ----
        const bool allv  = __all(am_cur > 0);             // wave-uniform
        const bool needc = (n0 + 63) > (q0 + w16);        // wave-uniform
        bf16x8 pf[2];
        {
            float tm = -3.0e38f;
            if (allv) {
                if (needc) {
                    #pragma unroll
                    for (int ni = 0; ni < 4; ++ni)
                        #pragma unroll
                        for (int rg = 0; rg < 4; ++rg) {
                            const int n_loc = ni * 16 + g4 + rg;
                            const float sv = ((n0 + n_loc) <= qrow) ? st[ni][rg] : NEGV;
                            st[ni][rg] = sv;
                            tm = fmaxf(tm, sv);
                        }
                } else {
                    #pragma unroll
                    for (int ni = 0; ni < 4; ++ni)
                        #pragma unroll
                        for (int rg = 0; rg < 4; ++rg)
                            tm = fmaxf(tm, st[ni][rg]);
                }
            } else {
                #pragma unroll
                for (int ni = 0; ni < 4; ++ni)
                    #pragma unroll
                    for (int rg = 0; rg < 4; ++rg) {
                        const int n_loc = ni * 16 + g4 + rg;
                        const bool ok = ((n0 + n_loc) <= qrow) && (__shfl(am_cur, n_loc) > 0);
                        const float sv = ok ? st[ni][rg] : NEGV;
                        st[ni][rg] = sv;
                        tm = fmaxf(tm, sv);
                    }
            }
            tm = fmaxf(tm, __shfl_xor(tm, 16));
            tm = fmaxf(tm, __shfl_xor(tm, 32));
            const bool skip = __all(tm <= mr + 7.0f);
            if (!skip) {
                const float mnew  = fmaxf(mr, tm);
                const float alpha = exp2f(mr - mnew);
                mr = mnew;
                #pragma unroll
                for (int di = 0; di < 4; ++di)
                    #pragma unroll
                    for (int rg = 0; rg < 4; ++rg)
                        oT[di][rg] *= alpha;
                lacc[0] *= alpha;
            }
            if (allv) {
                #pragma unroll
                for (int ni = 0; ni < 4; ++ni)
                    #pragma unroll
                    for (int rg = 0; rg < 4; ++rg)
                        pf[ni >> 1][((ni & 1) << 2) | rg] =
                            (__bf16)exp2f(st[ni][rg] - mr);
            } else {
                #pragma unroll
                for (int ni = 0; ni < 4; ++ni)
                    #pragma unroll
                    for (int rg = 0; rg < 4; ++rg) {
                        const float sv = st[ni][rg];
                        const float pv = (sv > -1.0e29f) ? exp2f(sv - mr) : 0.f;
                        pf[ni >> 1][((ni & 1) << 2) | rg] = (__bf16)pv;
                    }
            }
        }

        // ---- l-sum + O^T += V^T . P^T (phi-permuted k, contiguous b128) ----
        __builtin_amdgcn_s_setprio(1);
        lacc = __builtin_amdgcn_mfma_f32_16x16x32_bf16(onesf, pf[0], lacc, 0, 0, 0);
        lacc = __builtin_amdgcn_mfma_f32_16x16x32_bf16(onesf, pf[1], lacc, 0, 0, 0);
        #pragma unroll
        for (int di = 0; di < 4; ++di)
            #pragma unroll
            for (int kk = 0; kk < 2; ++kk) {
                const bf16x8 vfr = *(const bf16x8*)&Vts[(di * 16 + c16) * 72 + kk * 32 + g8];
                oT[di] = __builtin_amdgcn_mfma_f32_16x16x32_bf16(vfr, pf[kk], oT[di], 0, 0, 0);
            }
        __builtin_amdgcn_s_setprio(0);
    }

    // ---- epilogue: f32x4 stores ----
    const float inv = (lacc[0] > 0.f) ? 1.f / lacc[0] : 0.f;
    const int q = q0 + w16 + c16;
    #pragma unroll
    for (int di = 0; di < 4; ++di) {
        f32x4 ov;
        #pragma unroll
        for (int rg = 0; rg < 4; ++rg) ov[rg] = oT[di][rg] * inv;
        *(f32x4*)&out[((size_t)(b * M_ + q) * H_ + h) * 64 + di * 16 + g4] = ov;
    }
}

// ---------------------------------------------------------------------------
extern "C" void kernel_launch(void* const* d_in, const int* in_sizes, int n_in,
                              void* d_out, int out_size, void* d_ws, size_t ws_size,
                              hipStream_t stream)
{
    const float* Pq = (const float*)d_in[0];
    const float* Pk = (const float*)d_in[1];
    const float* Pv = (const float*)d_in[2];
    const float* Vq = (const float*)d_in[3];
    const float* Vk = (const float*)d_in[4];
    const float* Vv = (const float*)d_in[5];
    const float* bq = (const float*)d_in[6];
    const float* bk = (const float*)d_in[7];
    const float* bv = (const float*)d_in[8];
    const int*   am = (const int*)d_in[9];
    const int*   pid = (const int*)d_in[10];
    float* out = (float*)d_out;

    // workspace: tab 1MB | VTb 192KB (@1MB) | Qb,Kb,Vt bf16 16MB each (@2MB)
    float* tab = (float*)d_ws;
    unsigned short* VTb = (unsigned short*)((char*)d_ws + (1 << 20));
    unsigned short* Qb  = (unsigned short*)((char*)d_ws + (2 << 20));
    unsigned short* Kb = Qb + (size_t)B_ * H_ * M_ * 64;
    unsigned short* Vt = Kb + (size_t)B_ * H_ * M_ * 64;

    prep_kernel<<<dim3((B_ * M_ * 16 + 98304) / 256), dim3(256), 0, stream>>>(
        pid, Vq, Vk, Vv, tab, VTb);

    qkv_proj_mfma_kernel<<<dim3(16, 64, 3), dim3(256), 0, stream>>>(
        Pq, Pk, Pv, VTb, bq, bk, bv, tab, Qb, Kb, Vt);

    flash_mfma_kernel<<<dim3(2048), dim3(256), 0, stream>>>(
        Qb, Kb, Vt, am, out);
}